// Round 1
// baseline (1230.695 us; speedup 1.0000x reference)
//
#include <hip/hip_runtime.h>
#include <math.h>

#define NN 5000
#define NE 80000
#define EPSB 1e-3f

// ---------------------------------------------------------------- kernels ---

__global__ void k_deg(const int* __restrict__ ei, float* __restrict__ cnt) {
    int e = blockIdx.x * blockDim.x + threadIdx.x;
    if (e < NE) atomicAdd(&cnt[ei[NE + e]], 1.0f);
}

// layer-1 edge kernel: msg_e[o] = sum_i x[src][i] * relu(a*W1[i,o]+b1[i,o])
// i-range split across gridDim.y (2 slices of 18/17) for occupancy.
__global__ void k_edge1(const int* __restrict__ ei, const float* __restrict__ ea,
                        const float* __restrict__ x,
                        const float* __restrict__ W1, const float* __restrict__ b1,
                        float* __restrict__ summ1) {
    int e = blockIdx.x * blockDim.x + threadIdx.x;
    if (e >= NE) return;
    int ib = blockIdx.y * 18;
    int iend = (ib + 18 > 35) ? 35 : ib + 18;
    int src = ei[e], dst = ei[NE + e];
    float a = ea[e];
    float acc[35];
#pragma unroll
    for (int o = 0; o < 35; ++o) acc[o] = 0.f;
    for (int i = ib; i < iend; ++i) {
        float xv = x[src * 35 + i];
        const float* Wr = W1 + i * 35;   // wave-uniform address
        const float* br = b1 + i * 35;
#pragma unroll
        for (int o = 0; o < 35; ++o)
            acc[o] = fmaf(xv, fmaxf(0.f, fmaf(a, Wr[o], br[o])), acc[o]);
    }
    float* sp = summ1 + dst * 35;
#pragma unroll
    for (int o = 0; o < 35; ++o) atomicAdd(&sp[o], acc[o]);
}

__global__ void k_fin1(const float* __restrict__ x, const float* __restrict__ summ1,
                       const float* __restrict__ cnt,
                       const float* __restrict__ root1, const float* __restrict__ bias1,
                       const float* __restrict__ g, const float* __restrict__ be,
                       const float* __restrict__ rm, const float* __restrict__ rv,
                       float* __restrict__ x1) {
    int t = blockIdx.x * blockDim.x + threadIdx.x;
    if (t >= NN * 35) return;
    int n = t / 35, o = t - n * 35;
    float mean = summ1[t] / fmaxf(cnt[n], 1.0f);
    float r = 0.f;
#pragma unroll 7
    for (int i = 0; i < 35; ++i) r = fmaf(x[n * 35 + i], root1[i * 35 + o], r);
    float h = mean + r + bias1[o];
    float z = (h - rm[o]) * (g[o] * rsqrtf(rv[o] + EPSB)) + be[o];
    x1[t] = 1.f / (1.f + expf(-z));
}

// layer-3 edge kernel: o split across gridDim.y (5 chunks of 32)
__global__ void k_edge3(const int* __restrict__ ei, const float* __restrict__ ea,
                        const float* __restrict__ x1,
                        const float* __restrict__ W3, const float* __restrict__ b3,
                        float* __restrict__ summ3) {
    int e = blockIdx.x * blockDim.x + threadIdx.x;
    if (e >= NE) return;
    int ob = blockIdx.y * 32;
    int src = ei[e], dst = ei[NE + e];
    float a = ea[e];
    float acc[32];
#pragma unroll
    for (int o = 0; o < 32; ++o) acc[o] = 0.f;
    for (int i = 0; i < 35; ++i) {
        float xv = x1[src * 35 + i];
        const float* Wr = W3 + i * 160 + ob;  // wave-uniform address
        const float* br = b3 + i * 160 + ob;
#pragma unroll
        for (int o = 0; o < 32; ++o)
            acc[o] = fmaf(xv, fmaxf(0.f, fmaf(a, Wr[o], br[o])), acc[o]);
    }
    float* sp = summ3 + dst * 160 + ob;
#pragma unroll
    for (int o = 0; o < 32; ++o) atomicAdd(&sp[o], acc[o]);
}

__global__ void k_fin3(const float* __restrict__ x1, const float* __restrict__ summ3,
                       const float* __restrict__ cnt,
                       const float* __restrict__ root3, const float* __restrict__ bias3,
                       const float* __restrict__ g, const float* __restrict__ be,
                       const float* __restrict__ rm, const float* __restrict__ rv,
                       float* __restrict__ x3) {
    int n = blockIdx.x;
    int o = threadIdx.x;   // 160 threads
    int t = n * 160 + o;
    float mean = summ3[t] / fmaxf(cnt[n], 1.0f);
    float r = 0.f;
#pragma unroll 7
    for (int i = 0; i < 35; ++i) r = fmaf(x1[n * 35 + i], root3[i * 160 + o], r);
    float h = mean + r + bias3[o];
    float z = (h - rm[o]) * (g[o] * rsqrtf(rv[o] + EPSB)) + be[o];
    x3[t] = 1.f / (1.f + expf(-z));
}

// out = x3^T x3 : split-K (40 slices of 125 rows), 16x16 output tile per block.
__global__ void k_gram(const float* __restrict__ x3, float* __restrict__ out) {
    __shared__ float As[125][16];
    __shared__ float Bs[125][16];
    int ti = threadIdx.x & 15;
    int tj = threadIdx.x >> 4;
    int i0 = blockIdx.x * 16, j0 = blockIdx.y * 16;
    int k0 = blockIdx.z * 125;
    for (int r = tj; r < 125; r += 16) {
        As[r][ti] = x3[(k0 + r) * 160 + i0 + ti];
        Bs[r][ti] = x3[(k0 + r) * 160 + j0 + ti];
    }
    __syncthreads();
    float acc = 0.f;
#pragma unroll 5
    for (int r = 0; r < 125; ++r) acc = fmaf(As[r][ti], Bs[r][tj], acc);
    atomicAdd(&out[(i0 + ti) * 160 + (j0 + tj)], acc);
}

// ----------------------------------------------------------------- launch ---

extern "C" void kernel_launch(void* const* d_in, const int* in_sizes, int n_in,
                              void* d_out, int out_size, void* d_ws, size_t ws_size,
                              hipStream_t stream) {
    const float* x     = (const float*)d_in[0];
    const int*   ei    = (const int*)d_in[1];   // [2,E] int32 (src row, dst row)
    const float* ea    = (const float*)d_in[2];
    const float* W1    = (const float*)d_in[3];
    const float* b1    = (const float*)d_in[4];
    const float* root1 = (const float*)d_in[5];
    const float* bias1 = (const float*)d_in[6];
    const float* g1    = (const float*)d_in[7];
    const float* be1   = (const float*)d_in[8];
    const float* rm1   = (const float*)d_in[9];
    const float* rv1   = (const float*)d_in[10];
    const float* W3    = (const float*)d_in[11];
    const float* b3    = (const float*)d_in[12];
    const float* root3 = (const float*)d_in[13];
    const float* bias3 = (const float*)d_in[14];
    const float* g3    = (const float*)d_in[15];
    const float* be3   = (const float*)d_in[16];
    const float* rm3   = (const float*)d_in[17];
    const float* rv3   = (const float*)d_in[18];
    float* out = (float*)d_out;

    float* ws    = (float*)d_ws;
    float* cnt   = ws;                 // 5000   (padded to 5120)
    float* summ1 = ws + 5120;          // 175000 (padded to 175104)
    float* x1    = ws + 180224;        // 175000
    float* summ3 = ws + 355328;        // 800000
    float* x3    = ws + 1155328;       // 800000
    // total: 1955328 floats = 7.8 MB

    // harness poisons ws/out with 0xAA before every timed call
    hipMemsetAsync(d_ws, 0, (size_t)1155328 * 4, stream);   // cnt, summ1, summ3
    hipMemsetAsync(d_out, 0, (size_t)160 * 160 * 4, stream);

    int eb = (NE + 255) / 256;
    k_deg  <<<eb, 256, 0, stream>>>(ei, cnt);
    k_edge1<<<dim3(eb, 2), 256, 0, stream>>>(ei, ea, x, W1, b1, summ1);
    k_fin1 <<<(NN * 35 + 255) / 256, 256, 0, stream>>>(x, summ1, cnt, root1, bias1,
                                                       g1, be1, rm1, rv1, x1);
    k_edge3<<<dim3(eb, 5), 256, 0, stream>>>(ei, ea, x1, W3, b3, summ3);
    k_fin3 <<<NN, 160, 0, stream>>>(x1, summ3, cnt, root3, bias3, g3, be3, rm3, rv3, x3);
    k_gram <<<dim3(10, 10, 40), 256, 0, stream>>>(x3, out);
}

// Round 2
// 319.325 us; speedup vs baseline: 3.8541x; 3.8541x over previous
//
#include <hip/hip_runtime.h>
#include <math.h>

#define NN 5000
#define NE 80000
#define EPSB 1e-3f
#define GZ 25   // gram k-slices (200 rows each)

// ---------------------------------------------------------- CSR build ------

__global__ void k_count(const int* __restrict__ ei, int* __restrict__ counts) {
    int e = blockIdx.x * blockDim.x + threadIdx.x;
    if (e < NE) atomicAdd(&counts[ei[NE + e]], 1);
}

// one block, 256 threads, 20 elements each -> exclusive offsets[0..5000]
__global__ void k_scan(const int* __restrict__ counts, int* __restrict__ offs) {
    __shared__ int part[256];
    int t = threadIdx.x;
    int base = t * 20;
    int loc[20];
    int s = 0;
#pragma unroll
    for (int j = 0; j < 20; ++j) {
        int idx = base + j;
        int v = (idx < NN) ? counts[idx] : 0;
        loc[j] = s; s += v;
    }
    part[t] = s;
    __syncthreads();
    for (int off = 1; off < 256; off <<= 1) {
        int v = (t >= off) ? part[t - off] : 0;
        __syncthreads();
        part[t] += v;
        __syncthreads();
    }
    int pre = (t > 0) ? part[t - 1] : 0;
#pragma unroll
    for (int j = 0; j < 20; ++j) {
        int idx = base + j;
        if (idx < NN) offs[idx] = pre + loc[j];
    }
    if (t == 255) offs[NN] = part[255];
}

__global__ void k_fill(const int* __restrict__ ei, const int* __restrict__ offs,
                       int* __restrict__ cursor, int* __restrict__ elist) {
    int e = blockIdx.x * blockDim.x + threadIdx.x;
    if (e >= NE) return;
    int dst = ei[NE + e];
    int p = atomicAdd(&cursor[dst], 1);
    elist[offs[dst] + p] = e;
}

// ------------------------------------------------- fused NNConv layer 1 ----
// block = 128 threads = 2 nodes x 64 lanes (lanes o<35 compute; all stage)

__global__ __launch_bounds__(128) void k_conv1(
    const int* __restrict__ ei, const float* __restrict__ ea,
    const int* __restrict__ offs, const int* __restrict__ elist,
    const float* __restrict__ x,
    const float* __restrict__ W1, const float* __restrict__ b1,
    const float* __restrict__ root1, const float* __restrict__ bias1,
    const float* __restrict__ g, const float* __restrict__ be,
    const float* __restrict__ rm, const float* __restrict__ rv,
    float* __restrict__ x1)
{
    __shared__ __align__(16) float xs[2][32][36];
    __shared__ float aa[2][32];
    __shared__ int   ss[2][32];
    __shared__ float xn[2][35];
    int tid = threadIdx.x;
    int g_ = tid >> 6;
    int o  = tid & 63;
    bool act = (o < 35);
    int oc = act ? o : 0;
    int n0 = blockIdx.x * 2;
    int offA = offs[n0], offB = offs[n0 + 1], offC = offs[n0 + 2];
    int degA = offB - offA, degB = offC - offB;
    int n   = n0 + g_;
    int deg = g_ ? degB : degA;

    if (tid < 70) { int gg = tid / 35, i = tid % 35; xn[gg][i] = x[(n0 + gg) * 35 + i]; }
    __syncthreads();

    float rdot = 0.f;
    float w[35], bb[35];
#pragma unroll
    for (int i = 0; i < 35; ++i) rdot = fmaf(xn[g_][i], root1[i * 35 + oc], rdot);
#pragma unroll
    for (int i = 0; i < 35; ++i) { w[i] = W1[i * 35 + oc]; bb[i] = b1[i * 35 + oc]; }

    float acc = 0.f;
    int maxdeg = max(degA, degB);
    int nch = (maxdeg + 31) >> 5;
    for (int c = 0; c < nch; ++c) {
        int cb = c << 5;
        __syncthreads();
        if (tid < 64) {
            int gg = tid >> 5, el = tid & 31;
            int dg = gg ? degB : degA;
            int of = gg ? offB : offA;
            if (cb + el < dg) {
                int e = elist[of + cb + el];
                aa[gg][el] = ea[e];
                ss[gg][el] = ei[e];       // src node
            }
        }
        __syncthreads();
        for (int idx = tid; idx < 2240; idx += 128) {
            int gg = idx / 1120; int rem = idx - gg * 1120;
            int el = rem / 35;   int i   = rem - el * 35;
            int dg = gg ? degB : degA;
            if (cb + el < dg) xs[gg][el][i] = x[ss[gg][el] * 35 + i];
        }
        __syncthreads();
        int nel = min(32, deg - cb);
        for (int el = 0; el < nel; ++el) {
            float a = aa[g_][el];
            const float4* xr = (const float4*)(&xs[g_][el][0]);
#pragma unroll
            for (int q = 0; q < 9; ++q) {
                float4 v = xr[q];
                int i0 = q * 4;
                acc = fmaf(v.x, fmaxf(0.f, fmaf(a, w[i0], bb[i0])), acc);
                if (i0 + 1 < 35) acc = fmaf(v.y, fmaxf(0.f, fmaf(a, w[i0 + 1], bb[i0 + 1])), acc);
                if (i0 + 2 < 35) acc = fmaf(v.z, fmaxf(0.f, fmaf(a, w[i0 + 2], bb[i0 + 2])), acc);
                if (i0 + 3 < 35) acc = fmaf(v.w, fmaxf(0.f, fmaf(a, w[i0 + 3], bb[i0 + 3])), acc);
            }
        }
    }
    if (act) {
        float mean = acc / fmaxf((float)deg, 1.0f);
        float h = mean + rdot + bias1[o];
        float z = (h - rm[o]) * (g[o] * rsqrtf(rv[o] + EPSB)) + be[o];
        x1[n * 35 + o] = 1.f / (1.f + expf(-z));
    }
}

// ------------------------------------------------- fused NNConv layer 3 ----
// block = 320 threads = 2 nodes x 160 lanes

__global__ __launch_bounds__(320) void k_conv3(
    const int* __restrict__ ei, const float* __restrict__ ea,
    const int* __restrict__ offs, const int* __restrict__ elist,
    const float* __restrict__ x1,
    const float* __restrict__ W3, const float* __restrict__ b3,
    const float* __restrict__ root3, const float* __restrict__ bias3,
    const float* __restrict__ g, const float* __restrict__ be,
    const float* __restrict__ rm, const float* __restrict__ rv,
    float* __restrict__ x3)
{
    __shared__ __align__(16) float xs[2][32][36];
    __shared__ float aa[2][32];
    __shared__ int   ss[2][32];
    __shared__ float xn[2][35];
    int tid = threadIdx.x;
    int g_ = tid / 160;
    int o  = tid % 160;
    int n0 = blockIdx.x * 2;
    int offA = offs[n0], offB = offs[n0 + 1], offC = offs[n0 + 2];
    int degA = offB - offA, degB = offC - offB;
    int n   = n0 + g_;
    int deg = g_ ? degB : degA;

    if (tid < 70) { int gg = tid / 35, i = tid % 35; xn[gg][i] = x1[(n0 + gg) * 35 + i]; }
    __syncthreads();

    float rdot = 0.f;
    float w[35], bb[35];
#pragma unroll
    for (int i = 0; i < 35; ++i) rdot = fmaf(xn[g_][i], root3[i * 160 + o], rdot);
#pragma unroll
    for (int i = 0; i < 35; ++i) { w[i] = W3[i * 160 + o]; bb[i] = b3[i * 160 + o]; }

    float acc = 0.f;
    int maxdeg = max(degA, degB);
    int nch = (maxdeg + 31) >> 5;
    for (int c = 0; c < nch; ++c) {
        int cb = c << 5;
        __syncthreads();
        if (tid < 64) {
            int gg = tid >> 5, el = tid & 31;
            int dg = gg ? degB : degA;
            int of = gg ? offB : offA;
            if (cb + el < dg) {
                int e = elist[of + cb + el];
                aa[gg][el] = ea[e];
                ss[gg][el] = ei[e];
            }
        }
        __syncthreads();
        for (int idx = tid; idx < 2240; idx += 320) {
            int gg = idx / 1120; int rem = idx - gg * 1120;
            int el = rem / 35;   int i   = rem - el * 35;
            int dg = gg ? degB : degA;
            if (cb + el < dg) xs[gg][el][i] = x1[ss[gg][el] * 35 + i];
        }
        __syncthreads();
        int nel = min(32, deg - cb);
        for (int el = 0; el < nel; ++el) {
            float a = aa[g_][el];
            const float4* xr = (const float4*)(&xs[g_][el][0]);
#pragma unroll
            for (int q = 0; q < 9; ++q) {
                float4 v = xr[q];
                int i0 = q * 4;
                acc = fmaf(v.x, fmaxf(0.f, fmaf(a, w[i0], bb[i0])), acc);
                if (i0 + 1 < 35) acc = fmaf(v.y, fmaxf(0.f, fmaf(a, w[i0 + 1], bb[i0 + 1])), acc);
                if (i0 + 2 < 35) acc = fmaf(v.z, fmaxf(0.f, fmaf(a, w[i0 + 2], bb[i0 + 2])), acc);
                if (i0 + 3 < 35) acc = fmaf(v.w, fmaxf(0.f, fmaf(a, w[i0 + 3], bb[i0 + 3])), acc);
            }
        }
    }
    float mean = acc / fmaxf((float)deg, 1.0f);
    float h = mean + rdot + bias3[o];
    float z = (h - rm[o]) * (g[o] * rsqrtf(rv[o] + EPSB)) + be[o];
    x3[n * 160 + o] = 1.f / (1.f + expf(-z));
}

// ----------------------------------------------------------- gram ----------
// grid (3,3,GZ), block (16,16): each thread a 4x4 out sub-tile, no LDS, no atomics

__global__ void k_gram(const float* __restrict__ x3, float* __restrict__ part) {
    int tx = threadIdx.x, ty = threadIdx.y;
    int i = blockIdx.x * 64 + tx * 4;
    int j = blockIdx.y * 64 + ty * 4;
    if (i >= 160 || j >= 160) return;
    int k0 = blockIdx.z * 200;
    float acc[4][4];
#pragma unroll
    for (int r = 0; r < 4; ++r)
#pragma unroll
        for (int c = 0; c < 4; ++c) acc[r][c] = 0.f;
    for (int k = k0; k < k0 + 200; ++k) {
        float4 av = *(const float4*)&x3[k * 160 + i];
        float4 bv = *(const float4*)&x3[k * 160 + j];
        float ar[4] = {av.x, av.y, av.z, av.w};
        float br[4] = {bv.x, bv.y, bv.z, bv.w};
#pragma unroll
        for (int r = 0; r < 4; ++r)
#pragma unroll
            for (int c = 0; c < 4; ++c) acc[r][c] = fmaf(ar[r], br[c], acc[r][c]);
    }
    float* pp = part + (size_t)blockIdx.z * 25600;
#pragma unroll
    for (int r = 0; r < 4; ++r)
#pragma unroll
        for (int c = 0; c < 4; ++c) pp[(i + r) * 160 + (j + c)] = acc[r][c];
}

__global__ void k_reduce(const float* __restrict__ part, float* __restrict__ out) {
    int t = blockIdx.x * 256 + threadIdx.x;
    if (t >= 25600) return;
    float s = 0.f;
#pragma unroll
    for (int z = 0; z < GZ; ++z) s += part[z * 25600 + t];
    out[t] = s;
}

// ----------------------------------------------------------------- launch --

extern "C" void kernel_launch(void* const* d_in, const int* in_sizes, int n_in,
                              void* d_out, int out_size, void* d_ws, size_t ws_size,
                              hipStream_t stream) {
    const float* x     = (const float*)d_in[0];
    const int*   ei    = (const int*)d_in[1];
    const float* ea    = (const float*)d_in[2];
    const float* W1    = (const float*)d_in[3];
    const float* b1    = (const float*)d_in[4];
    const float* root1 = (const float*)d_in[5];
    const float* bias1 = (const float*)d_in[6];
    const float* g1    = (const float*)d_in[7];
    const float* be1   = (const float*)d_in[8];
    const float* rm1   = (const float*)d_in[9];
    const float* rv1   = (const float*)d_in[10];
    const float* W3    = (const float*)d_in[11];
    const float* b3    = (const float*)d_in[12];
    const float* root3 = (const float*)d_in[13];
    const float* bias3 = (const float*)d_in[14];
    const float* g3    = (const float*)d_in[15];
    const float* be3   = (const float*)d_in[16];
    const float* rm3   = (const float*)d_in[17];
    const float* rv3   = (const float*)d_in[18];
    float* out = (float*)d_out;

    int*   counts = (int*)d_ws;              // [5120]
    int*   cursor = counts + 5120;           // [5120]
    int*   offs   = cursor + 5120;           // [5120] (5001 used)
    int*   elist  = offs + 5120;             // [80128]
    float* x1     = (float*)(elist + 80128); // [175104]
    float* x3     = x1 + 175104;             // [800000]
    float* part   = x3 + 800000;             // [640000]
    // total 6.84 MB of ws

    // zero only counts+cursor (harness poisons ws with 0xAA)
    hipMemsetAsync(d_ws, 0, (size_t)2 * 5120 * sizeof(int), stream);

    int eb = (NE + 255) / 256;
    k_count<<<eb, 256, 0, stream>>>(ei, counts);
    k_scan <<<1, 256, 0, stream>>>(counts, offs);
    k_fill <<<eb, 256, 0, stream>>>(ei, offs, cursor, elist);
    k_conv1<<<2500, 128, 0, stream>>>(ei, ea, offs, elist, x, W1, b1, root1, bias1,
                                      g1, be1, rm1, rv1, x1);
    k_conv3<<<2500, 320, 0, stream>>>(ei, ea, offs, elist, x1, W3, b3, root3, bias3,
                                      g3, be3, rm3, rv3, x3);
    k_gram <<<dim3(3, 3, GZ), dim3(16, 16), 0, stream>>>(x3, part);
    k_reduce<<<(25600 + 255) / 256, 256, 0, stream>>>(part, out);
}

// Round 3
// 299.828 us; speedup vs baseline: 4.1047x; 1.0650x over previous
//
#include <hip/hip_runtime.h>
#include <math.h>

#define NN 5000
#define NE 80000
#define EPSB 1e-3f
#define GZ 25   // gram k-slices (200 rows each)

// bf16 helpers (RNE pack / unpack)
__device__ __forceinline__ unsigned int f2bf(float f) {
    unsigned int u = __float_as_uint(f);
    return (u + 0x7FFFu + ((u >> 16) & 1u)) >> 16;
}
__device__ __forceinline__ float bf2f(unsigned short h) {
    return __uint_as_float(((unsigned int)h) << 16);
}

// ---------------------------------------------------------- CSR build ------

__global__ void k_count(const int* __restrict__ ei, int* __restrict__ counts) {
    int e = blockIdx.x * blockDim.x + threadIdx.x;
    if (e < NE) atomicAdd(&counts[ei[NE + e]], 1);
}

__global__ void k_scan(const int* __restrict__ counts, int* __restrict__ offs) {
    __shared__ int part[256];
    int t = threadIdx.x;
    int base = t * 20;
    int loc[20];
    int s = 0;
#pragma unroll
    for (int j = 0; j < 20; ++j) {
        int idx = base + j;
        int v = (idx < NN) ? counts[idx] : 0;
        loc[j] = s; s += v;
    }
    part[t] = s;
    __syncthreads();
    for (int off = 1; off < 256; off <<= 1) {
        int v = (t >= off) ? part[t - off] : 0;
        __syncthreads();
        part[t] += v;
        __syncthreads();
    }
    int pre = (t > 0) ? part[t - 1] : 0;
#pragma unroll
    for (int j = 0; j < 20; ++j) {
        int idx = base + j;
        if (idx < NN) offs[idx] = pre + loc[j];
    }
    if (t == 255) offs[NN] = part[255];
}

__global__ void k_fill(const int* __restrict__ ei, const int* __restrict__ offs,
                       int* __restrict__ cursor, int* __restrict__ elist) {
    int e = blockIdx.x * blockDim.x + threadIdx.x;
    if (e >= NE) return;
    int dst = ei[NE + e];
    int p = atomicAdd(&cursor[dst], 1);
    elist[offs[dst] + p] = e;
}

// pad x [5000][35] -> x_p [5000][36] (col 35 = 0) for aligned float4 loads
__global__ void k_pad(const float* __restrict__ x, float* __restrict__ x_p) {
    int t = blockIdx.x * blockDim.x + threadIdx.x;
    if (t >= NN * 36) return;
    int n = t / 36, i = t - n * 36;
    x_p[t] = (i < 35) ? x[n * 35 + i] : 0.f;
}

// ------------------------------------- layer 1 phase 1: per-edge messages --
// thread = one edge, all 35 (36) outputs. W1/b1 staged in LDS (padded, zero
// rows/cols beyond 35 keep the padded lanes exactly 0).

__global__ __launch_bounds__(256) void k_edge1(
    const int* __restrict__ ei, const float* __restrict__ ea,
    const float* __restrict__ x_p,
    const float* __restrict__ W1, const float* __restrict__ b1,
    unsigned short* __restrict__ msg1)
{
    __shared__ float wls[36][36];
    __shared__ float bls[36][36];
    for (int idx = threadIdx.x; idx < 1296; idx += 256) {
        int i = idx / 36, o = idx - i * 36;
        bool in = (i < 35) && (o < 35);
        wls[i][o] = in ? W1[i * 35 + o] : 0.f;
        bls[i][o] = in ? b1[i * 35 + o] : 0.f;
    }
    __syncthreads();
    int e = blockIdx.x * 256 + threadIdx.x;
    if (e >= NE) return;
    int src = ei[e];
    float a = ea[e];
    const float4* xp4 = (const float4*)(x_p + src * 36);
    float acc[36];
#pragma unroll
    for (int o = 0; o < 36; ++o) acc[o] = 0.f;
    float4 xv = xp4[0];
#pragma unroll 1
    for (int q = 0; q < 9; ++q) {
        float4 xn = (q < 8) ? xp4[q + 1] : xv;
        float xs4[4] = {xv.x, xv.y, xv.z, xv.w};
#pragma unroll
        for (int r = 0; r < 4; ++r) {
            int i = q * 4 + r;
            float xvr = xs4[r];
            const float4* wr = (const float4*)(&wls[i][0]);
            const float4* br = (const float4*)(&bls[i][0]);
#pragma unroll
            for (int oq = 0; oq < 9; ++oq) {
                float4 wv = wr[oq], bv = br[oq];
                int o0 = oq * 4;
                acc[o0 + 0] = fmaf(xvr, fmaxf(0.f, fmaf(a, wv.x, bv.x)), acc[o0 + 0]);
                acc[o0 + 1] = fmaf(xvr, fmaxf(0.f, fmaf(a, wv.y, bv.y)), acc[o0 + 1]);
                acc[o0 + 2] = fmaf(xvr, fmaxf(0.f, fmaf(a, wv.z, bv.z)), acc[o0 + 2]);
                acc[o0 + 3] = fmaf(xvr, fmaxf(0.f, fmaf(a, wv.w, bv.w)), acc[o0 + 3]);
            }
        }
        xv = xn;
    }
    // pack 36 bf16 -> 18 uints -> 9 aligned uint2 stores (row = 72 B)
    unsigned int pk[18];
#pragma unroll
    for (int k = 0; k < 18; ++k)
        pk[k] = f2bf(acc[2 * k]) | (f2bf(acc[2 * k + 1]) << 16);
    uint2* dst = (uint2*)(msg1 + (size_t)e * 36);
#pragma unroll
    for (int j = 0; j < 9; ++j) dst[j] = make_uint2(pk[2 * j], pk[2 * j + 1]);
}

// ----------------------------------- layer 1 phase 2: gather + finalize ----

__global__ __launch_bounds__(256) void k_sum1(
    const int* __restrict__ offs, const int* __restrict__ elist,
    const unsigned short* __restrict__ msg1,
    const float* __restrict__ x_p,
    const float* __restrict__ root1, const float* __restrict__ bias1,
    const float* __restrict__ g, const float* __restrict__ be,
    const float* __restrict__ rm, const float* __restrict__ rv,
    float* __restrict__ x1p)
{
    int t = blockIdx.x * 256 + threadIdx.x;
    if (t >= NN * 36) return;
    int n = t / 36, o = t - n * 36;
    if (o == 35) { x1p[t] = 0.f; return; }   // pad column
    int off = offs[n];
    int deg = offs[n + 1] - off;
    float s = 0.f;
    for (int j = 0; j < deg; ++j) {
        int e = elist[off + j];
        s += bf2f(msg1[(size_t)e * 36 + o]);
    }
    float mean = s / fmaxf((float)deg, 1.0f);
    float r = 0.f;
#pragma unroll 7
    for (int i = 0; i < 35; ++i) r = fmaf(x_p[n * 36 + i], root1[i * 35 + o], r);
    float h = mean + r + bias1[o];
    float z = (h - rm[o]) * (g[o] * rsqrtf(rv[o] + EPSB)) + be[o];
    x1p[t] = 1.f / (1.f + expf(-z));
}

// ------------------------------------- layer 3 phase 1: per-edge messages --
// thread = one edge x 32-output chunk (gridDim.y = 5). msg layout [5][E][32].

__global__ __launch_bounds__(256) void k_edge3(
    const int* __restrict__ ei, const float* __restrict__ ea,
    const float* __restrict__ x1p,
    const float* __restrict__ W3, const float* __restrict__ b3,
    unsigned short* __restrict__ msg3)
{
    __shared__ float wls[36][32];
    __shared__ float bls[36][32];
    int ob = blockIdx.y * 32;
    for (int idx = threadIdx.x; idx < 1152; idx += 256) {
        int i = idx >> 5, o = idx & 31;
        bool in = (i < 35);
        wls[i][o] = in ? W3[i * 160 + ob + o] : 0.f;
        bls[i][o] = in ? b3[i * 160 + ob + o] : 0.f;
    }
    __syncthreads();
    int e = blockIdx.x * 256 + threadIdx.x;
    if (e >= NE) return;
    int src = ei[e];
    float a = ea[e];
    const float4* xp4 = (const float4*)(x1p + src * 36);
    float acc[32];
#pragma unroll
    for (int o = 0; o < 32; ++o) acc[o] = 0.f;
    float4 xv = xp4[0];
#pragma unroll 1
    for (int q = 0; q < 9; ++q) {
        float4 xn = (q < 8) ? xp4[q + 1] : xv;
        float xs4[4] = {xv.x, xv.y, xv.z, xv.w};
#pragma unroll
        for (int r = 0; r < 4; ++r) {
            int i = q * 4 + r;
            float xvr = xs4[r];
            const float4* wr = (const float4*)(&wls[i][0]);
            const float4* br = (const float4*)(&bls[i][0]);
#pragma unroll
            for (int oq = 0; oq < 8; ++oq) {
                float4 wv = wr[oq], bv = br[oq];
                int o0 = oq * 4;
                acc[o0 + 0] = fmaf(xvr, fmaxf(0.f, fmaf(a, wv.x, bv.x)), acc[o0 + 0]);
                acc[o0 + 1] = fmaf(xvr, fmaxf(0.f, fmaf(a, wv.y, bv.y)), acc[o0 + 1]);
                acc[o0 + 2] = fmaf(xvr, fmaxf(0.f, fmaf(a, wv.z, bv.z)), acc[o0 + 2]);
                acc[o0 + 3] = fmaf(xvr, fmaxf(0.f, fmaf(a, wv.w, bv.w)), acc[o0 + 3]);
            }
        }
        xv = xn;
    }
    unsigned int pk[16];
#pragma unroll
    for (int k = 0; k < 16; ++k)
        pk[k] = f2bf(acc[2 * k]) | (f2bf(acc[2 * k + 1]) << 16);
    uint4* dst = (uint4*)(msg3 + ((size_t)blockIdx.y * NE + e) * 32);
#pragma unroll
    for (int j = 0; j < 4; ++j)
        dst[j] = make_uint4(pk[4 * j], pk[4 * j + 1], pk[4 * j + 2], pk[4 * j + 3]);
}

// ----------------------------------- layer 3 phase 2: gather + finalize ----

__global__ __launch_bounds__(320) void k_sum3(
    const int* __restrict__ offs, const int* __restrict__ elist,
    const unsigned short* __restrict__ msg3,
    const float* __restrict__ x1p,
    const float* __restrict__ root3, const float* __restrict__ bias3,
    const float* __restrict__ g, const float* __restrict__ be,
    const float* __restrict__ rm, const float* __restrict__ rv,
    float* __restrict__ x3)
{
    __shared__ float xn[2][36];
    int tid = threadIdx.x;
    int g_ = tid / 160;
    int o  = tid - g_ * 160;
    int n  = blockIdx.x * 2 + g_;
    if (tid < 72) xn[tid / 36][tid % 36] = x1p[(blockIdx.x * 2 + tid / 36) * 36 + tid % 36];
    __syncthreads();
    int off = offs[n];
    int deg = offs[n + 1] - off;
    int chunk = o >> 5, oo = o & 31;
    const unsigned short* base = msg3 + (size_t)chunk * NE * 32 + oo;
    float s = 0.f;
    for (int j = 0; j < deg; ++j) {
        int e = elist[off + j];
        s += bf2f(base[(size_t)e * 32]);
    }
    float mean = s / fmaxf((float)deg, 1.0f);
    float r = 0.f;
#pragma unroll 7
    for (int i = 0; i < 35; ++i) r = fmaf(xn[g_][i], root3[i * 160 + o], r);
    float h = mean + r + bias3[o];
    float z = (h - rm[o]) * (g[o] * rsqrtf(rv[o] + EPSB)) + be[o];
    x3[n * 160 + o] = 1.f / (1.f + expf(-z));
}

// ----------------------------------------------------------- gram ----------

__global__ void k_gram(const float* __restrict__ x3, float* __restrict__ part) {
    int tx = threadIdx.x, ty = threadIdx.y;
    int i = blockIdx.x * 64 + tx * 4;
    int j = blockIdx.y * 64 + ty * 4;
    if (i >= 160 || j >= 160) return;
    int k0 = blockIdx.z * 200;
    float acc[4][4];
#pragma unroll
    for (int r = 0; r < 4; ++r)
#pragma unroll
        for (int c = 0; c < 4; ++c) acc[r][c] = 0.f;
    for (int k = k0; k < k0 + 200; ++k) {
        float4 av = *(const float4*)&x3[k * 160 + i];
        float4 bv = *(const float4*)&x3[k * 160 + j];
        float ar[4] = {av.x, av.y, av.z, av.w};
        float br[4] = {bv.x, bv.y, bv.z, bv.w};
#pragma unroll
        for (int r = 0; r < 4; ++r)
#pragma unroll
            for (int c = 0; c < 4; ++c) acc[r][c] = fmaf(ar[r], br[c], acc[r][c]);
    }
    float* pp = part + (size_t)blockIdx.z * 25600;
#pragma unroll
    for (int r = 0; r < 4; ++r)
#pragma unroll
        for (int c = 0; c < 4; ++c) pp[(i + r) * 160 + (j + c)] = acc[r][c];
}

__global__ void k_reduce(const float* __restrict__ part, float* __restrict__ out) {
    int t = blockIdx.x * 256 + threadIdx.x;
    if (t >= 25600) return;
    float s = 0.f;
#pragma unroll
    for (int z = 0; z < GZ; ++z) s += part[z * 25600 + t];
    out[t] = s;
}

// ----------------------------------------------------------------- launch --

extern "C" void kernel_launch(void* const* d_in, const int* in_sizes, int n_in,
                              void* d_out, int out_size, void* d_ws, size_t ws_size,
                              hipStream_t stream) {
    const float* x     = (const float*)d_in[0];
    const int*   ei    = (const int*)d_in[1];
    const float* ea    = (const float*)d_in[2];
    const float* W1    = (const float*)d_in[3];
    const float* b1    = (const float*)d_in[4];
    const float* root1 = (const float*)d_in[5];
    const float* bias1 = (const float*)d_in[6];
    const float* g1    = (const float*)d_in[7];
    const float* be1   = (const float*)d_in[8];
    const float* rm1   = (const float*)d_in[9];
    const float* rv1   = (const float*)d_in[10];
    const float* W3    = (const float*)d_in[11];
    const float* b3    = (const float*)d_in[12];
    const float* root3 = (const float*)d_in[13];
    const float* bias3 = (const float*)d_in[14];
    const float* g3    = (const float*)d_in[15];
    const float* be3   = (const float*)d_in[16];
    const float* rm3   = (const float*)d_in[17];
    const float* rv3   = (const float*)d_in[18];
    float* out = (float*)d_out;

    // ---- workspace layout (byte offsets, all 16B-aligned) ----
    char* wsb = (char*)d_ws;
    int*   counts = (int*)(wsb + 0);                    //  20480 B
    int*   cursor = (int*)(wsb + 20480);                //  20480 B
    int*   offs   = (int*)(wsb + 40960);                //  20480 B
    int*   elist  = (int*)(wsb + 61440);                // 320512 B -> end 381952
    float* x_p    = (float*)(wsb + 381952);             // 720000 B -> end 1101952
    float* x1p    = (float*)(wsb + 1101952);            // 720000 B -> end 1821952
    float* x3     = (float*)(wsb + 1821952);            // 3.2 MB  -> end 5021952
    unsigned short* msg1 = (unsigned short*)(wsb + 5021952);  // 5.76 MB -> end 10781952
    float* part   = (float*)(wsb + 5021952);            // aliases msg1 (dead by gram time)
    unsigned short* msg3 = (unsigned short*)(wsb + 10781952); // 25.6 MB -> end 36381952

    hipMemsetAsync(d_ws, 0, (size_t)2 * 5120 * sizeof(int), stream);  // counts+cursor

    int eb = (NE + 255) / 256;
    k_pad  <<<(NN * 36 + 255) / 256, 256, 0, stream>>>(x, x_p);
    k_count<<<eb, 256, 0, stream>>>(ei, counts);
    k_scan <<<1, 256, 0, stream>>>(counts, offs);
    k_fill <<<eb, 256, 0, stream>>>(ei, offs, cursor, elist);
    k_edge1<<<eb, 256, 0, stream>>>(ei, ea, x_p, W1, b1, msg1);
    k_sum1 <<<(NN * 36 + 255) / 256, 256, 0, stream>>>(offs, elist, msg1, x_p,
                                                       root1, bias1, g1, be1, rm1, rv1, x1p);
    k_edge3<<<dim3(eb, 5), 256, 0, stream>>>(ei, ea, x1p, W3, b3, msg3);
    k_sum3 <<<2500, 320, 0, stream>>>(offs, elist, msg3, x1p,
                                      root3, bias3, g3, be3, rm3, rv3, x3);
    k_gram <<<dim3(3, 3, GZ), dim3(16, 16), 0, stream>>>(x3, part);
    k_reduce<<<(25600 + 255) / 256, 256, 0, stream>>>(part, out);
}

// Round 6
// 240.060 us; speedup vs baseline: 5.1266x; 1.2490x over previous
//
#include <hip/hip_runtime.h>
#include <math.h>

#define NN 5000
#define NE 80000
#define EPSB 1e-3f
#define GZ 100   // gram k-slices (50 rows each)

// bf16 helpers (RNE pack / unpack)
__device__ __forceinline__ unsigned int f2bf(float f) {
    unsigned int u = __float_as_uint(f);
    return (u + 0x7FFFu + ((u >> 16) & 1u)) >> 16;
}
__device__ __forceinline__ float bf2f(unsigned short h) {
    return __uint_as_float(((unsigned int)h) << 16);
}

// ------------------------------------------- prep: pad x + degree count ----

__global__ void k_prep(const float* __restrict__ x, float* __restrict__ x_p,
                       const int* __restrict__ ei, int* __restrict__ counts) {
    int t = blockIdx.x * 256 + threadIdx.x;
    if (t < NN * 36) {
        int n = t / 36, i = t - n * 36;
        x_p[t] = (i < 35) ? x[n * 35 + i] : 0.f;
    }
    if (t < NE) atomicAdd(&counts[ei[NE + t]], 1);
}

__global__ void k_scan(const int* __restrict__ counts, int* __restrict__ offs) {
    __shared__ int ps[256];
    int t = threadIdx.x;
    int base = t * 20;
    int loc[20];
    int s = 0;
#pragma unroll
    for (int j = 0; j < 20; ++j) {
        int idx = base + j;
        int v = (idx < NN) ? counts[idx] : 0;
        loc[j] = s; s += v;
    }
    ps[t] = s;
    __syncthreads();
    for (int off = 1; off < 256; off <<= 1) {
        int v = (t >= off) ? ps[t - off] : 0;
        __syncthreads();
        ps[t] += v;
        __syncthreads();
    }
    int pre = (t > 0) ? ps[t - 1] : 0;
#pragma unroll
    for (int j = 0; j < 20; ++j) {
        int idx = base + j;
        if (idx < NN) offs[idx] = pre + loc[j];
    }
    if (t == 255) offs[NN] = ps[255];
}

// per-edge CSR slot (messages get written directly in CSR order)
__global__ void k_fill(const int* __restrict__ ei, const int* __restrict__ offs,
                       int* __restrict__ cursor, int* __restrict__ eslot) {
    int e = blockIdx.x * blockDim.x + threadIdx.x;
    if (e >= NE) return;
    int dst = ei[NE + e];
    int p = atomicAdd(&cursor[dst], 1);
    eslot[e] = offs[dst] + p;
}

// ------------------------------------- layer 1 phase 1: per-edge messages --

__global__ __launch_bounds__(256) void k_edge1(
    const int* __restrict__ ei, const float* __restrict__ ea,
    const int* __restrict__ eslot,
    const float* __restrict__ x_p,
    const float* __restrict__ W1, const float* __restrict__ b1,
    unsigned short* __restrict__ msg1)
{
    __shared__ float wls[36][36];
    __shared__ float bls[36][36];
    for (int idx = threadIdx.x; idx < 1296; idx += 256) {
        int i = idx / 36, o = idx - i * 36;
        bool in = (i < 35) && (o < 35);
        wls[i][o] = in ? W1[i * 35 + o] : 0.f;
        bls[i][o] = in ? b1[i * 35 + o] : 0.f;
    }
    __syncthreads();
    int e = blockIdx.x * 256 + threadIdx.x;
    if (e >= NE) return;
    int src = ei[e];
    float a = ea[e];
    const float4* xp4 = (const float4*)(x_p + src * 36);
    float acc[36];
#pragma unroll
    for (int o = 0; o < 36; ++o) acc[o] = 0.f;
    float4 xv = xp4[0];
#pragma unroll 1
    for (int q = 0; q < 9; ++q) {
        float4 xn = (q < 8) ? xp4[q + 1] : xv;
        float xs4[4] = {xv.x, xv.y, xv.z, xv.w};
#pragma unroll
        for (int r = 0; r < 4; ++r) {
            int i = q * 4 + r;
            float xvr = xs4[r];
            const float4* wr = (const float4*)(&wls[i][0]);
            const float4* br = (const float4*)(&bls[i][0]);
#pragma unroll
            for (int oq = 0; oq < 9; ++oq) {
                float4 wv = wr[oq], bv = br[oq];
                int o0 = oq * 4;
                acc[o0 + 0] = fmaf(xvr, fmaxf(0.f, fmaf(a, wv.x, bv.x)), acc[o0 + 0]);
                acc[o0 + 1] = fmaf(xvr, fmaxf(0.f, fmaf(a, wv.y, bv.y)), acc[o0 + 1]);
                acc[o0 + 2] = fmaf(xvr, fmaxf(0.f, fmaf(a, wv.z, bv.z)), acc[o0 + 2]);
                acc[o0 + 3] = fmaf(xvr, fmaxf(0.f, fmaf(a, wv.w, bv.w)), acc[o0 + 3]);
            }
        }
        xv = xn;
    }
    unsigned int pk[18];
#pragma unroll
    for (int k = 0; k < 18; ++k)
        pk[k] = f2bf(acc[2 * k]) | (f2bf(acc[2 * k + 1]) << 16);
    uint2* dst = (uint2*)(msg1 + (size_t)eslot[e] * 36);
#pragma unroll
    for (int j = 0; j < 9; ++j) dst[j] = make_uint2(pk[2 * j], pk[2 * j + 1]);
}

// ----------------------------------- layer 1 phase 2: gather + finalize ----

__global__ __launch_bounds__(256) void k_sum1(
    const int* __restrict__ offs,
    const unsigned short* __restrict__ msg1,
    const float* __restrict__ x_p,
    const float* __restrict__ root1, const float* __restrict__ bias1,
    const float* __restrict__ g, const float* __restrict__ be,
    const float* __restrict__ rm, const float* __restrict__ rv,
    float* __restrict__ x1p)
{
    int t = blockIdx.x * 256 + threadIdx.x;
    if (t >= NN * 36) return;
    int n = t / 36, o = t - n * 36;
    if (o == 35) { x1p[t] = 0.f; return; }
    int off = offs[n];
    int deg = offs[n + 1] - off;
    const unsigned short* base = msg1 + (size_t)off * 36 + o;
    float s = 0.f;
    for (int j = 0; j < deg; ++j) s += bf2f(base[(size_t)j * 36]);
    float mean = s / fmaxf((float)deg, 1.0f);
    float r = 0.f;
#pragma unroll 7
    for (int i = 0; i < 35; ++i) r = fmaf(x_p[n * 36 + i], root1[i * 35 + o], r);
    float h = mean + r + bias1[o];
    float z = (h - rm[o]) * (g[o] * rsqrtf(rv[o] + EPSB)) + be[o];
    x1p[t] = 1.f / (1.f + expf(-z));
}

// ------------------------------------- layer 3 phase 1: per-edge messages --
// thread = one edge x 32-output chunk (gridDim.y = 5). msg layout [5][slot][32].

__global__ __launch_bounds__(256) void k_edge3(
    const int* __restrict__ ei, const float* __restrict__ ea,
    const int* __restrict__ eslot,
    const float* __restrict__ x1p,
    const float* __restrict__ W3, const float* __restrict__ b3,
    unsigned short* __restrict__ msg3)
{
    __shared__ float wls[36][32];
    __shared__ float bls[36][32];
    int ob = blockIdx.y * 32;
    for (int idx = threadIdx.x; idx < 1152; idx += 256) {
        int i = idx >> 5, o = idx & 31;
        bool in = (i < 35);
        wls[i][o] = in ? W3[i * 160 + ob + o] : 0.f;
        bls[i][o] = in ? b3[i * 160 + ob + o] : 0.f;
    }
    __syncthreads();
    int e = blockIdx.x * 256 + threadIdx.x;
    if (e >= NE) return;
    int src = ei[e];
    float a = ea[e];
    const float4* xp4 = (const float4*)(x1p + src * 36);
    float acc[32];
#pragma unroll
    for (int o = 0; o < 32; ++o) acc[o] = 0.f;
    float4 xv = xp4[0];
#pragma unroll 1
    for (int q = 0; q < 9; ++q) {
        float4 xn = (q < 8) ? xp4[q + 1] : xv;
        float xs4[4] = {xv.x, xv.y, xv.z, xv.w};
#pragma unroll
        for (int r = 0; r < 4; ++r) {
            int i = q * 4 + r;
            float xvr = xs4[r];
            const float4* wr = (const float4*)(&wls[i][0]);
            const float4* br = (const float4*)(&bls[i][0]);
#pragma unroll
            for (int oq = 0; oq < 8; ++oq) {
                float4 wv = wr[oq], bv = br[oq];
                int o0 = oq * 4;
                acc[o0 + 0] = fmaf(xvr, fmaxf(0.f, fmaf(a, wv.x, bv.x)), acc[o0 + 0]);
                acc[o0 + 1] = fmaf(xvr, fmaxf(0.f, fmaf(a, wv.y, bv.y)), acc[o0 + 1]);
                acc[o0 + 2] = fmaf(xvr, fmaxf(0.f, fmaf(a, wv.z, bv.z)), acc[o0 + 2]);
                acc[o0 + 3] = fmaf(xvr, fmaxf(0.f, fmaf(a, wv.w, bv.w)), acc[o0 + 3]);
            }
        }
        xv = xn;
    }
    unsigned int pk[16];
#pragma unroll
    for (int k = 0; k < 16; ++k)
        pk[k] = f2bf(acc[2 * k]) | (f2bf(acc[2 * k + 1]) << 16);
    uint4* dst = (uint4*)(msg3 + ((size_t)blockIdx.y * NE + eslot[e]) * 32);
#pragma unroll
    for (int j = 0; j < 4; ++j)
        dst[j] = make_uint4(pk[4 * j], pk[4 * j + 1], pk[4 * j + 2], pk[4 * j + 3]);
}

// ----------------------------------- layer 3 phase 2: gather + finalize ----
// block 320 = 4 nodes x 80 lanes; each lane 2 adjacent outputs (one uint load/row)

__global__ __launch_bounds__(320) void k_sum3(
    const int* __restrict__ offs,
    const unsigned short* __restrict__ msg3,
    const float* __restrict__ x1p,
    const float* __restrict__ root3, const float* __restrict__ bias3,
    const float* __restrict__ g, const float* __restrict__ be,
    const float* __restrict__ rm, const float* __restrict__ rv,
    float* __restrict__ x3)
{
    __shared__ float xn[4][36];
    int tid = threadIdx.x;
    int g_ = tid / 80;
    int o2 = tid - g_ * 80;
    int o  = o2 * 2;
    int n  = blockIdx.x * 4 + g_;
    if (tid < 144) xn[tid / 36][tid % 36] = x1p[(blockIdx.x * 4 + tid / 36) * 36 + tid % 36];
    __syncthreads();
    int off = offs[n];
    int deg = offs[n + 1] - off;
    int chunk = o >> 5, oo = o & 31;
    const unsigned short* base = msg3 + ((size_t)chunk * NE + off) * 32 + oo;
    float s0 = 0.f, s1 = 0.f;
    for (int j = 0; j < deg; ++j) {
        unsigned int u = *(const unsigned int*)(base + (size_t)j * 32);
        s0 += bf2f((unsigned short)(u & 0xffff));
        s1 += bf2f((unsigned short)(u >> 16));
    }
    float inv = 1.f / fmaxf((float)deg, 1.0f);
    float m0 = s0 * inv, m1 = s1 * inv;
    float r0 = 0.f, r1 = 0.f;
#pragma unroll 7
    for (int i = 0; i < 35; ++i) {
        float xvi = xn[g_][i];
        r0 = fmaf(xvi, root3[i * 160 + o], r0);
        r1 = fmaf(xvi, root3[i * 160 + o + 1], r1);
    }
    float h0 = m0 + r0 + bias3[o];
    float h1 = m1 + r1 + bias3[o + 1];
    float z0 = (h0 - rm[o]) * (g[o] * rsqrtf(rv[o] + EPSB)) + be[o];
    float z1 = (h1 - rm[o + 1]) * (g[o + 1] * rsqrtf(rv[o + 1] + EPSB)) + be[o + 1];
    float2 res = make_float2(1.f / (1.f + expf(-z0)), 1.f / (1.f + expf(-z1)));
    *(float2*)(x3 + n * 160 + o) = res;
}

// ----------------------------------------------------------- gram ----------
// grid (3,3,GZ) k-chunk 50; unrolled for load ILP

__global__ void k_gram(const float* __restrict__ x3, float* __restrict__ part) {
    int tx = threadIdx.x, ty = threadIdx.y;
    int i = blockIdx.x * 64 + tx * 4;
    int j = blockIdx.y * 64 + ty * 4;
    if (i >= 160 || j >= 160) return;
    int k0 = blockIdx.z * 50;
    float acc[4][4];
#pragma unroll
    for (int r = 0; r < 4; ++r)
#pragma unroll
        for (int c = 0; c < 4; ++c) acc[r][c] = 0.f;
#pragma unroll 5
    for (int k = k0; k < k0 + 50; ++k) {
        float4 av = *(const float4*)&x3[k * 160 + i];
        float4 bv = *(const float4*)&x3[k * 160 + j];
        float ar[4] = {av.x, av.y, av.z, av.w};
        float br[4] = {bv.x, bv.y, bv.z, bv.w};
#pragma unroll
        for (int r = 0; r < 4; ++r)
#pragma unroll
            for (int c = 0; c < 4; ++c) acc[r][c] = fmaf(ar[r], br[c], acc[r][c]);
    }
    float* pp = part + (size_t)blockIdx.z * 25600;
#pragma unroll
    for (int r = 0; r < 4; ++r)
#pragma unroll
        for (int c = 0; c < 4; ++c) pp[(i + r) * 160 + (j + c)] = acc[r][c];
}

__global__ void k_reduce(const float* __restrict__ part, float* __restrict__ out) {
    int t = blockIdx.x * 256 + threadIdx.x;
    if (t >= 25600) return;
    float s = 0.f;
#pragma unroll 10
    for (int z = 0; z < GZ; ++z) s += part[(size_t)z * 25600 + t];
    out[t] = s;
}

// ----------------------------------------------------------------- launch --

extern "C" void kernel_launch(void* const* d_in, const int* in_sizes, int n_in,
                              void* d_out, int out_size, void* d_ws, size_t ws_size,
                              hipStream_t stream) {
    const float* x     = (const float*)d_in[0];
    const int*   ei    = (const int*)d_in[1];
    const float* ea    = (const float*)d_in[2];
    const float* W1    = (const float*)d_in[3];
    const float* b1    = (const float*)d_in[4];
    const float* root1 = (const float*)d_in[5];
    const float* bias1 = (const float*)d_in[6];
    const float* g1    = (const float*)d_in[7];
    const float* be1   = (const float*)d_in[8];
    const float* rm1   = (const float*)d_in[9];
    const float* rv1   = (const float*)d_in[10];
    const float* W3    = (const float*)d_in[11];
    const float* b3    = (const float*)d_in[12];
    const float* root3 = (const float*)d_in[13];
    const float* bias3 = (const float*)d_in[14];
    const float* g3    = (const float*)d_in[15];
    const float* be3   = (const float*)d_in[16];
    const float* rm3   = (const float*)d_in[17];
    const float* rv3   = (const float*)d_in[18];
    float* out = (float*)d_out;

    // ---- workspace layout (byte offsets, all 16B-aligned) ----
    char* wsb = (char*)d_ws;
    int*   counts = (int*)(wsb + 0);                    //  20480 B
    int*   cursor = (int*)(wsb + 20480);                //  20480 B
    int*   offs   = (int*)(wsb + 40960);                //  20480 B
    int*   eslot  = (int*)(wsb + 61440);                // 320512 B -> end 381952
    float* x_p    = (float*)(wsb + 381952);             // 720000 B -> end 1101952
    float* x1p    = (float*)(wsb + 1101952);            // 720000 B -> end 1821952
    float* x3     = (float*)(wsb + 1821952);            // 3.2 MB  -> end 5021952
    unsigned short* msg1 = (unsigned short*)(wsb + 5021952);  // 5.76 MB -> end 10781952
    unsigned short* msg3 = (unsigned short*)(wsb + 10781952); // 25.6 MB -> end 36381952
    float* part   = (float*)(wsb + 10781952);           // 10.24 MB, aliases msg3 (dead)

    hipMemsetAsync(d_ws, 0, (size_t)2 * 5120 * sizeof(int), stream);  // counts+cursor

    int eb = (NE + 255) / 256;
    k_prep <<<(NN * 36 + 255) / 256, 256, 0, stream>>>(x, x_p, ei, counts);
    k_scan <<<1, 256, 0, stream>>>(counts, offs);
    k_fill <<<eb, 256, 0, stream>>>(ei, offs, cursor, eslot);
    k_edge1<<<eb, 256, 0, stream>>>(ei, ea, eslot, x_p, W1, b1, msg1);
    k_sum1 <<<(NN * 36 + 255) / 256, 256, 0, stream>>>(offs, msg1, x_p,
                                                       root1, bias1, g1, be1, rm1, rv1, x1p);
    k_edge3<<<dim3(eb, 5), 256, 0, stream>>>(ei, ea, eslot, x1p, W3, b3, msg3);
    k_sum3 <<<1250, 320, 0, stream>>>(offs, msg3, x1p,
                                      root3, bias3, g3, be3, rm3, rv3, x3);
    k_gram <<<dim3(3, 3, GZ), dim3(16, 16), 0, stream>>>(x3, part);
    k_reduce<<<(25600 + 255) / 256, 256, 0, stream>>>(part, out);
}